// Round 1
// baseline (3214.323 us; speedup 1.0000x reference)
//
#include <hip/hip_runtime.h>

// ---------------------------------------------------------------------------
// TAGCN node regression: 3 TAGConv layers (K=4) + linear head, fp32.
// Strategy: build CSR (by dst) once per launch -> all 12 propagations are
// gather-only (no atomics). Thread = (node, feature); wave lanes share a
// node's edge list (broadcast loads) and gather contiguous feature rows.
// ---------------------------------------------------------------------------

__global__ void degcount_k(const int* __restrict__ dst, const float* __restrict__ w,
                           float* __restrict__ deg, int* __restrict__ cnt, int E) {
  int e = blockIdx.x * blockDim.x + threadIdx.x;
  if (e >= E) return;
  int d = dst[e];
  atomicAdd(&deg[d], w[e]);
  atomicAdd(&cnt[d], 1);
}

__global__ void dinv_k(float* __restrict__ deg, int n) {
  int i = blockIdx.x * blockDim.x + threadIdx.x;
  if (i >= n) return;
  float d = deg[i];
  deg[i] = (d > 0.f) ? rsqrtf(fmaxf(d, 1e-30f)) : 0.f;
}

// 3-phase exclusive scan of cnt -> ptr (256 elems per block)
__global__ void scan_blocks(const int* __restrict__ cnt, int* __restrict__ ptr,
                            int* __restrict__ bsum, int n) {
  __shared__ int s[256];
  int tid = threadIdx.x;
  int i = blockIdx.x * 256 + tid;
  int v = (i < n) ? cnt[i] : 0;
  s[tid] = v;
  __syncthreads();
#pragma unroll
  for (int off = 1; off < 256; off <<= 1) {
    int t = (tid >= off) ? s[tid - off] : 0;
    __syncthreads();
    s[tid] += t;
    __syncthreads();
  }
  if (i < n) ptr[i] = s[tid] - v;  // local exclusive
  if (tid == 255) bsum[blockIdx.x] = s[255];
}

__global__ void scan_sums(int* __restrict__ bsum, int nb) {
  __shared__ int s[512];
  int tid = threadIdx.x;
  int v = (tid < nb) ? bsum[tid] : 0;
  s[tid] = v;
  __syncthreads();
#pragma unroll
  for (int off = 1; off < 512; off <<= 1) {
    int t = (tid >= off) ? s[tid - off] : 0;
    __syncthreads();
    s[tid] += t;
    __syncthreads();
  }
  if (tid < nb) bsum[tid] = s[tid] - v;  // exclusive over block sums
}

__global__ void scan_add(int* __restrict__ ptr, const int* __restrict__ bsum,
                         int* __restrict__ cursor, int n, int E) {
  int i = blockIdx.x * blockDim.x + threadIdx.x;
  if (i < n) {
    int p = ptr[i] + bsum[i >> 8];
    ptr[i] = p;
    cursor[i] = p;
  }
  if (i == 0) ptr[n] = E;
}

// scatter edges into CSR slots; fold gcn_norm value into payload
__global__ void fill_k(const int* __restrict__ src, const int* __restrict__ dst,
                       const float* __restrict__ w, const float* __restrict__ dinv,
                       int* __restrict__ cursor, int* __restrict__ csrc,
                       float* __restrict__ cval, int E) {
  int e = blockIdx.x * blockDim.x + threadIdx.x;
  if (e >= E) return;
  int s = src[e], d = dst[e];
  float nv = dinv[s] * w[e] * dinv[d];
  int pos = atomicAdd(&cursor[d], 1);
  csrc[pos] = s;
  cval[pos] = nv;
}

// h_out[node][f] = sum_e cval[e] * h_in[csrc[e]][f]
template <int F>
__global__ void prop_k(const int* __restrict__ ptr, const int* __restrict__ csrc,
                       const float* __restrict__ cval, const float* __restrict__ hin,
                       float* __restrict__ hout, int n) {
  int gid = blockIdx.x * blockDim.x + threadIdx.x;
  int node = gid / F;
  int f = gid & (F - 1);
  if (node >= n) return;
  int e0 = ptr[node], e1 = ptr[node + 1];
  float a = 0.f;
  int e = e0;
  for (; e + 1 < e1; e += 2) {  // 2-deep gather pipelining
    int s0 = csrc[e], s1 = csrc[e + 1];
    float w0 = cval[e], w1 = cval[e + 1];
    a += w0 * hin[s0 * F + f];
    a += w1 * hin[s1 * F + f];
  }
  if (e < e1) a += cval[e] * hin[csrc[e] * F + f];
  hout[node * F + f] = a;
}

// out[node][j] (+)= sum_i h[node][i] * W[i][j]; optional bias+leaky epilogue
template <int FIN, bool ACC, bool EPI>
__global__ void matmul_k(const float* __restrict__ h, const float* __restrict__ W,
                         const float* __restrict__ bias, float* __restrict__ out, int n) {
  int gid = blockIdx.x * blockDim.x + threadIdx.x;
  int node = gid >> 6, j = gid & 63;
  if (node >= n) return;
  const float* hr = h + node * FIN;
  float a = ACC ? out[node * 64 + j] : 0.f;
#pragma unroll
  for (int i = 0; i < FIN; ++i) a = fmaf(hr[i], W[i * 64 + j], a);
  if (EPI) {
    a += bias[j];
    a = (a >= 0.f) ? a : 0.01f * a;
  }
  out[node * 64 + j] = a;
}

// out[node] = sum_j h[node][j]*Wout[j] + bout  (wave-per-node reduction)
__global__ void out_k(const float* __restrict__ h, const float* __restrict__ Wout,
                      const float* __restrict__ bout, float* __restrict__ out, int n) {
  int gid = blockIdx.x * blockDim.x + threadIdx.x;
  int node = gid >> 6;
  int lane = threadIdx.x & 63;
  if (node >= n) return;
  float v = h[node * 64 + lane] * Wout[lane];
#pragma unroll
  for (int off = 32; off > 0; off >>= 1) v += __shfl_down(v, off, 64);
  if (lane == 0) out[node] = v + bout[0];
}

extern "C" void kernel_launch(void* const* d_in, const int* in_sizes, int n_in,
                              void* d_out, int out_size, void* d_ws, size_t ws_size,
                              hipStream_t stream) {
  const float* x    = (const float*)d_in[0];
  const int*   ei   = (const int*)d_in[1];
  const float* ew   = (const float*)d_in[2];
  const float* W1   = (const float*)d_in[4];
  const float* b1   = (const float*)d_in[5];
  const float* W2   = (const float*)d_in[6];
  const float* b2   = (const float*)d_in[7];
  const float* Wout = (const float*)d_in[8];
  const float* bout = (const float*)d_in[9];
  float* out = (float*)d_out;

  const int N = in_sizes[0] / 16;
  const int E = in_sizes[2];
  const int* src = ei;
  const int* dst = ei + E;

  char* ws = (char*)d_ws;
  size_t off = 0;
  auto alloc = [&](size_t bytes) {
    char* p = ws + off;
    off = (off + bytes + 255) & ~(size_t)255;
    return p;
  };
  float* deg  = (float*)alloc((size_t)N * 4);        // becomes dinv in-place
  int*   cnt  = (int*)alloc((size_t)N * 4);          // counts, then cursor
  int*   ptr  = (int*)alloc(((size_t)N + 1) * 4);
  int*   bsum = (int*)alloc(4096);
  int*   csrc = (int*)alloc((size_t)E * 4);
  float* cval = (float*)alloc((size_t)E * 4);
  float* B0   = (float*)alloc((size_t)N * 64 * 4);
  float* B1   = (float*)alloc((size_t)N * 64 * 4);
  float* B2   = (float*)alloc((size_t)N * 64 * 4);

  // zero deg..cnt (contiguous, includes pad)
  size_t zbytes = (size_t)((char*)cnt - (char*)deg) + (size_t)N * 4;
  hipMemsetAsync(deg, 0, zbytes, stream);

  int gE = (E + 255) / 256;
  int gN = (N + 255) / 256;
  int nb = gN;  // 256 elems/block in scan_blocks
  degcount_k<<<gE, 256, 0, stream>>>(dst, ew, deg, cnt, E);
  dinv_k<<<gN, 256, 0, stream>>>(deg, N);
  scan_blocks<<<nb, 256, 0, stream>>>(cnt, ptr, bsum, N);
  scan_sums<<<1, 512, 0, stream>>>(bsum, nb);
  scan_add<<<gN, 256, 0, stream>>>(ptr, bsum, cnt, N, E);
  fill_k<<<gE, 256, 0, stream>>>(src, dst, ew, deg, cnt, csrc, cval, E);

  int g16 = (N * 16 + 255) / 256;
  int g64 = (N * 64 + 255) / 256;

  // ---- Layer 1 (F_in=16), acc in B2, props ping-pong B0/B1 ----
  matmul_k<16, false, false><<<g64, 256, 0, stream>>>(x, W1 + 0 * 1024, nullptr, B2, N);
  prop_k<16><<<g16, 256, 0, stream>>>(ptr, csrc, cval, x, B0, N);
  matmul_k<16, true, false><<<g64, 256, 0, stream>>>(B0, W1 + 1 * 1024, nullptr, B2, N);
  prop_k<16><<<g16, 256, 0, stream>>>(ptr, csrc, cval, B0, B1, N);
  matmul_k<16, true, false><<<g64, 256, 0, stream>>>(B1, W1 + 2 * 1024, nullptr, B2, N);
  prop_k<16><<<g16, 256, 0, stream>>>(ptr, csrc, cval, B1, B0, N);
  matmul_k<16, true, false><<<g64, 256, 0, stream>>>(B0, W1 + 3 * 1024, nullptr, B2, N);
  prop_k<16><<<g16, 256, 0, stream>>>(ptr, csrc, cval, B0, B1, N);
  matmul_k<16, true, true><<<g64, 256, 0, stream>>>(B1, W1 + 4 * 1024, b1, B2, N);

  // ---- Layer 2 (F=64): input B2, acc B1 ----
  const float* W2a = W2;
  matmul_k<64, false, false><<<g64, 256, 0, stream>>>(B2, W2a + 0 * 4096, nullptr, B1, N);
  prop_k<64><<<g64, 256, 0, stream>>>(ptr, csrc, cval, B2, B0, N);
  matmul_k<64, true, false><<<g64, 256, 0, stream>>>(B0, W2a + 1 * 4096, nullptr, B1, N);
  prop_k<64><<<g64, 256, 0, stream>>>(ptr, csrc, cval, B0, B2, N);
  matmul_k<64, true, false><<<g64, 256, 0, stream>>>(B2, W2a + 2 * 4096, nullptr, B1, N);
  prop_k<64><<<g64, 256, 0, stream>>>(ptr, csrc, cval, B2, B0, N);
  matmul_k<64, true, false><<<g64, 256, 0, stream>>>(B0, W2a + 3 * 4096, nullptr, B1, N);
  prop_k<64><<<g64, 256, 0, stream>>>(ptr, csrc, cval, B0, B2, N);
  matmul_k<64, true, true><<<g64, 256, 0, stream>>>(B2, W2a + 4 * 4096, b2, B1, N);

  // ---- Layer 3 (F=64): input B1, acc B2 ----
  const float* W2b = W2 + 5 * 4096;
  matmul_k<64, false, false><<<g64, 256, 0, stream>>>(B1, W2b + 0 * 4096, nullptr, B2, N);
  prop_k<64><<<g64, 256, 0, stream>>>(ptr, csrc, cval, B1, B0, N);
  matmul_k<64, true, false><<<g64, 256, 0, stream>>>(B0, W2b + 1 * 4096, nullptr, B2, N);
  prop_k<64><<<g64, 256, 0, stream>>>(ptr, csrc, cval, B0, B1, N);
  matmul_k<64, true, false><<<g64, 256, 0, stream>>>(B1, W2b + 2 * 4096, nullptr, B2, N);
  prop_k<64><<<g64, 256, 0, stream>>>(ptr, csrc, cval, B1, B0, N);
  matmul_k<64, true, false><<<g64, 256, 0, stream>>>(B0, W2b + 3 * 4096, nullptr, B2, N);
  prop_k<64><<<g64, 256, 0, stream>>>(ptr, csrc, cval, B0, B1, N);
  matmul_k<64, true, true><<<g64, 256, 0, stream>>>(B1, W2b + 4 * 4096, b2 + 64, B2, N);

  // ---- head ----
  out_k<<<g64, 256, 0, stream>>>(B2, Wout, bout, out, N);
}

// Round 2
// 2204.063 us; speedup vs baseline: 1.4584x; 1.4584x over previous
//
#include <hip/hip_runtime.h>

// ---------------------------------------------------------------------------
// TAGCN node regression: 3 TAGConv layers (K=4) + linear head, fp32.
// CSR-by-dst built once per launch; all 12 propagations are gather-only.
// R2: packed 64-bit degree atomic, packed int2 edge payload, float4-granular
// props (16 lanes/node @F=64) and float4-vectorized matmuls.
// ---------------------------------------------------------------------------

typedef unsigned long long u64;

// one 64-bit atomic per edge: [count:16 | sum_w Q16.32 fixed point:48]
__global__ void degcount_k(const int* __restrict__ dst, const float* __restrict__ w,
                           u64* __restrict__ pack, int E) {
  int e = blockIdx.x * blockDim.x + threadIdx.x;
  if (e >= E) return;
  int d = dst[e];
  u64 v = ((u64)1 << 48) | (u64)((double)w[e] * 4294967296.0);
  atomicAdd(&pack[d], v);
}

__global__ void decode_k(const u64* __restrict__ pack, float* __restrict__ dinv,
                         int* __restrict__ cnt, int n) {
  int i = blockIdx.x * blockDim.x + threadIdx.x;
  if (i >= n) return;
  u64 v = pack[i];
  cnt[i] = (int)(v >> 48);
  float d = (float)((double)(v & 0xFFFFFFFFFFFFULL) * (1.0 / 4294967296.0));
  dinv[i] = (d > 0.f) ? rsqrtf(fmaxf(d, 1e-30f)) : 0.f;
}

// 3-phase exclusive scan of cnt -> ptr (256 elems per block)
__global__ void scan_blocks(const int* __restrict__ cnt, int* __restrict__ ptr,
                            int* __restrict__ bsum, int n) {
  __shared__ int s[256];
  int tid = threadIdx.x;
  int i = blockIdx.x * 256 + tid;
  int v = (i < n) ? cnt[i] : 0;
  s[tid] = v;
  __syncthreads();
#pragma unroll
  for (int off = 1; off < 256; off <<= 1) {
    int t = (tid >= off) ? s[tid - off] : 0;
    __syncthreads();
    s[tid] += t;
    __syncthreads();
  }
  if (i < n) ptr[i] = s[tid] - v;  // local exclusive
  if (tid == 255) bsum[blockIdx.x] = s[255];
}

__global__ void scan_sums(int* __restrict__ bsum, int nb) {
  __shared__ int s[512];
  int tid = threadIdx.x;
  int v = (tid < nb) ? bsum[tid] : 0;
  s[tid] = v;
  __syncthreads();
#pragma unroll
  for (int off = 1; off < 512; off <<= 1) {
    int t = (tid >= off) ? s[tid - off] : 0;
    __syncthreads();
    s[tid] += t;
    __syncthreads();
  }
  if (tid < nb) bsum[tid] = s[tid] - v;  // exclusive over block sums
}

__global__ void scan_add(int* __restrict__ ptr, const int* __restrict__ bsum,
                         int* __restrict__ cursor, int n, int E) {
  int i = blockIdx.x * blockDim.x + threadIdx.x;
  if (i < n) {
    int p = ptr[i] + bsum[i >> 8];
    ptr[i] = p;
    cursor[i] = p;
  }
  if (i == 0) ptr[n] = E;
}

// scatter edges into CSR slots; payload = {src, folded gcn_norm} as one int2
__global__ void fill_k(const int* __restrict__ src, const int* __restrict__ dst,
                       const float* __restrict__ w, const float* __restrict__ dinv,
                       int* __restrict__ cursor, int2* __restrict__ ep, int E) {
  int e = blockIdx.x * blockDim.x + threadIdx.x;
  if (e >= E) return;
  int s = src[e], d = dst[e];
  float nv = dinv[s] * w[e] * dinv[d];
  int pos = atomicAdd(&cursor[d], 1);
  ep[pos] = make_int2(s, __float_as_int(nv));
}

// h_out[node][:] = sum_e w_e * h_in[src_e][:]; F4 = F/4 float4 lanes per node
template <int F4>
__global__ void prop_k(const int* __restrict__ ptr, const int2* __restrict__ ep,
                       const float4* __restrict__ hin, float4* __restrict__ hout, int n) {
  int gid = blockIdx.x * blockDim.x + threadIdx.x;
  int node = gid / F4;
  int f4 = gid & (F4 - 1);
  if (node >= n) return;
  int e0 = ptr[node], e1 = ptr[node + 1];
  float4 a = make_float4(0.f, 0.f, 0.f, 0.f);
  int e = e0;
  if ((e & 1) && e < e1) {  // peel to even index for aligned int4 loads
    int2 p = ep[e];
    float w0 = __int_as_float(p.y);
    float4 h0 = hin[(size_t)p.x * F4 + f4];
    a.x += w0 * h0.x; a.y += w0 * h0.y; a.z += w0 * h0.z; a.w += w0 * h0.w;
    ++e;
  }
  for (; e + 1 < e1; e += 2) {
    int4 p = *(const int4*)(ep + e);  // 2 edges, 16B aligned
    float w0 = __int_as_float(p.y), w1 = __int_as_float(p.w);
    float4 h0 = hin[(size_t)p.x * F4 + f4];
    float4 h1 = hin[(size_t)p.z * F4 + f4];
    a.x += w0 * h0.x; a.y += w0 * h0.y; a.z += w0 * h0.z; a.w += w0 * h0.w;
    a.x += w1 * h1.x; a.y += w1 * h1.y; a.z += w1 * h1.z; a.w += w1 * h1.w;
  }
  if (e < e1) {
    int2 p = ep[e];
    float w0 = __int_as_float(p.y);
    float4 h0 = hin[(size_t)p.x * F4 + f4];
    a.x += w0 * h0.x; a.y += w0 * h0.y; a.z += w0 * h0.z; a.w += w0 * h0.w;
  }
  hout[(size_t)node * F4 + f4] = a;
}

// out[node][4j4..4j4+3] (+)= h[node][:] @ W[:][...]; FIN4 = FIN/4
// thread = (node, j4); 16 lanes per node share broadcast h loads.
template <int FIN4, bool ACC, bool EPI>
__global__ void matmul_k(const float4* __restrict__ h4, const float4* __restrict__ W4,
                         const float* __restrict__ bias, float4* __restrict__ out4, int n) {
  int gid = blockIdx.x * blockDim.x + threadIdx.x;
  int node = gid >> 4, j4 = gid & 15;
  if (node >= n) return;
  const float4* hr = h4 + (size_t)node * FIN4;
  float4 a = ACC ? out4[(size_t)node * 16 + j4] : make_float4(0.f, 0.f, 0.f, 0.f);
#pragma unroll
  for (int i4 = 0; i4 < FIN4; ++i4) {
    float4 hv = hr[i4];  // broadcast within node's lane group
    float4 w0 = W4[(4 * i4 + 0) * 16 + j4];
    float4 w1 = W4[(4 * i4 + 1) * 16 + j4];
    float4 w2 = W4[(4 * i4 + 2) * 16 + j4];
    float4 w3 = W4[(4 * i4 + 3) * 16 + j4];
    a.x = fmaf(hv.x, w0.x, a.x); a.y = fmaf(hv.x, w0.y, a.y);
    a.z = fmaf(hv.x, w0.z, a.z); a.w = fmaf(hv.x, w0.w, a.w);
    a.x = fmaf(hv.y, w1.x, a.x); a.y = fmaf(hv.y, w1.y, a.y);
    a.z = fmaf(hv.y, w1.z, a.z); a.w = fmaf(hv.y, w1.w, a.w);
    a.x = fmaf(hv.z, w2.x, a.x); a.y = fmaf(hv.z, w2.y, a.y);
    a.z = fmaf(hv.z, w2.z, a.z); a.w = fmaf(hv.z, w2.w, a.w);
    a.x = fmaf(hv.w, w3.x, a.x); a.y = fmaf(hv.w, w3.y, a.y);
    a.z = fmaf(hv.w, w3.z, a.z); a.w = fmaf(hv.w, w3.w, a.w);
  }
  if (EPI) {
    float4 b = ((const float4*)bias)[j4];
    a.x += b.x; a.y += b.y; a.z += b.z; a.w += b.w;
    a.x = (a.x >= 0.f) ? a.x : 0.01f * a.x;
    a.y = (a.y >= 0.f) ? a.y : 0.01f * a.y;
    a.z = (a.z >= 0.f) ? a.z : 0.01f * a.z;
    a.w = (a.w >= 0.f) ? a.w : 0.01f * a.w;
  }
  out4[(size_t)node * 16 + j4] = a;
}

// out[node] = sum_j h[node][j]*Wout[j] + bout  (wave-per-node reduction)
__global__ void out_k(const float* __restrict__ h, const float* __restrict__ Wout,
                      const float* __restrict__ bout, float* __restrict__ out, int n) {
  int gid = blockIdx.x * blockDim.x + threadIdx.x;
  int node = gid >> 6;
  int lane = threadIdx.x & 63;
  if (node >= n) return;
  float v = h[(size_t)node * 64 + lane] * Wout[lane];
#pragma unroll
  for (int off = 32; off > 0; off >>= 1) v += __shfl_down(v, off, 64);
  if (lane == 0) out[node] = v + bout[0];
}

extern "C" void kernel_launch(void* const* d_in, const int* in_sizes, int n_in,
                              void* d_out, int out_size, void* d_ws, size_t ws_size,
                              hipStream_t stream) {
  const float* x    = (const float*)d_in[0];
  const int*   ei   = (const int*)d_in[1];
  const float* ew   = (const float*)d_in[2];
  const float* W1   = (const float*)d_in[4];
  const float* b1   = (const float*)d_in[5];
  const float* W2   = (const float*)d_in[6];
  const float* b2   = (const float*)d_in[7];
  const float* Wout = (const float*)d_in[8];
  const float* bout = (const float*)d_in[9];
  float* out = (float*)d_out;

  const int N = in_sizes[0] / 16;
  const int E = in_sizes[2];
  const int* src = ei;
  const int* dst = ei + E;

  char* ws = (char*)d_ws;
  size_t off = 0;
  auto alloc = [&](size_t bytes) {
    char* p = ws + off;
    off = (off + bytes + 255) & ~(size_t)255;
    return p;
  };
  u64*   pack = (u64*)alloc((size_t)N * 8);
  float* dinv = (float*)alloc((size_t)N * 4);
  int*   cnt  = (int*)alloc((size_t)N * 4);  // counts, then cursor
  int*   ptr  = (int*)alloc(((size_t)N + 1) * 4);
  int*   bsum = (int*)alloc(4096);
  int2*  ep   = (int2*)alloc((size_t)E * 8);
  float* B0   = (float*)alloc((size_t)N * 64 * 4);
  float* B1   = (float*)alloc((size_t)N * 64 * 4);
  float* B2   = (float*)alloc((size_t)N * 64 * 4);

  hipMemsetAsync(pack, 0, (size_t)N * 8, stream);

  int gE = (E + 255) / 256;
  int gN = (N + 255) / 256;
  int nb = gN;  // 256 elems/block in scan_blocks
  degcount_k<<<gE, 256, 0, stream>>>(dst, ew, pack, E);
  decode_k<<<gN, 256, 0, stream>>>(pack, dinv, cnt, N);
  scan_blocks<<<nb, 256, 0, stream>>>(cnt, ptr, bsum, N);
  scan_sums<<<1, 512, 0, stream>>>(bsum, nb);
  scan_add<<<gN, 256, 0, stream>>>(ptr, bsum, cnt, N, E);
  fill_k<<<gE, 256, 0, stream>>>(src, dst, ew, dinv, cnt, ep, E);

  int g4  = (N * 4 + 255) / 256;   // prop F=16 (4 lanes/node)
  int g16 = (N * 16 + 255) / 256;  // prop F=64 / matmul (16 lanes/node)
  int g64 = (N * 64 + 255) / 256;  // out_k

  const float4* x4 = (const float4*)x;
  float4* B04 = (float4*)B0; float4* B14 = (float4*)B1; float4* B24 = (float4*)B2;

  // ---- Layer 1 (F_in=16), acc in B2, props ping-pong B0/B1 ----
  matmul_k<4, false, false><<<g16, 256, 0, stream>>>(x4, (const float4*)(W1 + 0 * 1024), nullptr, B24, N);
  prop_k<4><<<g4, 256, 0, stream>>>(ptr, ep, x4, B04, N);
  matmul_k<4, true, false><<<g16, 256, 0, stream>>>(B04, (const float4*)(W1 + 1 * 1024), nullptr, B24, N);
  prop_k<4><<<g4, 256, 0, stream>>>(ptr, ep, B04, B14, N);
  matmul_k<4, true, false><<<g16, 256, 0, stream>>>(B14, (const float4*)(W1 + 2 * 1024), nullptr, B24, N);
  prop_k<4><<<g4, 256, 0, stream>>>(ptr, ep, B14, B04, N);
  matmul_k<4, true, false><<<g16, 256, 0, stream>>>(B04, (const float4*)(W1 + 3 * 1024), nullptr, B24, N);
  prop_k<4><<<g4, 256, 0, stream>>>(ptr, ep, B04, B14, N);
  matmul_k<4, true, true><<<g16, 256, 0, stream>>>(B14, (const float4*)(W1 + 4 * 1024), b1, B24, N);

  // ---- Layer 2 (F=64): input B2, acc B1 ----
  const float* W2a = W2;
  matmul_k<16, false, false><<<g16, 256, 0, stream>>>(B24, (const float4*)(W2a + 0 * 4096), nullptr, B14, N);
  prop_k<16><<<g16, 256, 0, stream>>>(ptr, ep, B24, B04, N);
  matmul_k<16, true, false><<<g16, 256, 0, stream>>>(B04, (const float4*)(W2a + 1 * 4096), nullptr, B14, N);
  prop_k<16><<<g16, 256, 0, stream>>>(ptr, ep, B04, B24, N);
  matmul_k<16, true, false><<<g16, 256, 0, stream>>>(B24, (const float4*)(W2a + 2 * 4096), nullptr, B14, N);
  prop_k<16><<<g16, 256, 0, stream>>>(ptr, ep, B24, B04, N);
  matmul_k<16, true, false><<<g16, 256, 0, stream>>>(B04, (const float4*)(W2a + 3 * 4096), nullptr, B14, N);
  prop_k<16><<<g16, 256, 0, stream>>>(ptr, ep, B04, B24, N);
  matmul_k<16, true, true><<<g16, 256, 0, stream>>>(B24, (const float4*)(W2a + 4 * 4096), b2, B14, N);

  // ---- Layer 3 (F=64): input B1, acc B2 ----
  const float* W2b = W2 + 5 * 4096;
  matmul_k<16, false, false><<<g16, 256, 0, stream>>>(B14, (const float4*)(W2b + 0 * 4096), nullptr, B24, N);
  prop_k<16><<<g16, 256, 0, stream>>>(ptr, ep, B14, B04, N);
  matmul_k<16, true, false><<<g16, 256, 0, stream>>>(B04, (const float4*)(W2b + 1 * 4096), nullptr, B24, N);
  prop_k<16><<<g16, 256, 0, stream>>>(ptr, ep, B04, B14, N);
  matmul_k<16, true, false><<<g16, 256, 0, stream>>>(B14, (const float4*)(W2b + 2 * 4096), nullptr, B24, N);
  prop_k<16><<<g16, 256, 0, stream>>>(ptr, ep, B14, B04, N);
  matmul_k<16, true, false><<<g16, 256, 0, stream>>>(B04, (const float4*)(W2b + 3 * 4096), nullptr, B24, N);
  prop_k<16><<<g16, 256, 0, stream>>>(ptr, ep, B04, B14, N);
  matmul_k<16, true, true><<<g16, 256, 0, stream>>>(B14, (const float4*)(W2b + 4 * 4096), b2 + 64, B24, N);

  // ---- head ----
  out_k<<<g64, 256, 0, stream>>>(B2, Wout, bout, out, N);
}

// Round 3
// 1632.871 us; speedup vs baseline: 1.9685x; 1.3498x over previous
//
#include <hip/hip_runtime.h>

// ---------------------------------------------------------------------------
// TAGCN node regression: 3 TAGConv layers (K=4) + linear head, fp32.
// CSR-by-dst built once per launch (rank captured from the degree atomic ->
// fill has NO atomics). Each propagation step is FUSED with its matmul
// accumulation (t = A*h gathered, then acc += t@W_k via LDS tile), the layer
// FIRST step folds the h0@W0 term, the LAST folds bias+LeakyReLU, and the
// network LAST folds the linear head reduction.
// ---------------------------------------------------------------------------

typedef unsigned long long u64;

// one 64-bit atomic per edge: [count:16 | sum_w Q16.32 fixed point:48]
// old count = this edge's rank within its dst bucket -> CSR slot, no 2nd atomic
__global__ void degcount_k(const int* __restrict__ dst, const float* __restrict__ w,
                           u64* __restrict__ pack, int* __restrict__ rank, int E) {
  int e = blockIdx.x * blockDim.x + threadIdx.x;
  if (e >= E) return;
  int d = dst[e];
  u64 v = ((u64)1 << 48) | (u64)((double)w[e] * 4294967296.0);
  u64 old = atomicAdd(&pack[d], v);
  rank[e] = (int)(old >> 48);
}

// scan (256/block) fused with degree decode -> dinv
__global__ void scan_blocks(const u64* __restrict__ pack, float* __restrict__ dinv,
                            int* __restrict__ ptr, int* __restrict__ bsum, int n) {
  __shared__ int s[256];
  int tid = threadIdx.x;
  int i = blockIdx.x * 256 + tid;
  int v = 0;
  if (i < n) {
    u64 p = pack[i];
    v = (int)(p >> 48);
    float d = (float)((double)(p & 0xFFFFFFFFFFFFULL) * (1.0 / 4294967296.0));
    dinv[i] = (d > 0.f) ? rsqrtf(fmaxf(d, 1e-30f)) : 0.f;
  }
  s[tid] = v;
  __syncthreads();
#pragma unroll
  for (int off = 1; off < 256; off <<= 1) {
    int t = (tid >= off) ? s[tid - off] : 0;
    __syncthreads();
    s[tid] += t;
    __syncthreads();
  }
  if (i < n) ptr[i] = s[tid] - v;
  if (tid == 255) bsum[blockIdx.x] = s[255];
}

__global__ void scan_sums(int* __restrict__ bsum, int nb) {
  __shared__ int s[512];
  int tid = threadIdx.x;
  int v = (tid < nb) ? bsum[tid] : 0;
  s[tid] = v;
  __syncthreads();
#pragma unroll
  for (int off = 1; off < 512; off <<= 1) {
    int t = (tid >= off) ? s[tid - off] : 0;
    __syncthreads();
    s[tid] += t;
    __syncthreads();
  }
  if (tid < nb) bsum[tid] = s[tid] - v;
}

__global__ void scan_add(int* __restrict__ ptr, const int* __restrict__ bsum, int n, int E) {
  int i = blockIdx.x * blockDim.x + threadIdx.x;
  if (i < n) ptr[i] += bsum[i >> 8];
  if (i == 0) ptr[n] = E;
}

// scatter edges into CSR slots (atomic-free); payload = {src, folded norm}
__global__ void fill_k(const int* __restrict__ src, const int* __restrict__ dst,
                       const float* __restrict__ w, const float* __restrict__ dinv,
                       const int* __restrict__ ptr, const int* __restrict__ rank,
                       int2* __restrict__ ep, int E) {
  int e = blockIdx.x * blockDim.x + threadIdx.x;
  if (e >= E) return;
  int s = src[e], d = dst[e];
  float nv = dinv[s] * w[e] * dinv[d];
  int pos = ptr[d] + rank[e];
  ep[pos] = make_int2(s, __float_as_int(nv));
}

// gather t[f4] = sum_e w_e * hin[src_e][f4]
template <int F4>
__device__ __forceinline__ float4 gather(const int* __restrict__ ptr, const int2* __restrict__ ep,
                                         const float4* __restrict__ hin, int node, int f4) {
  int e0 = ptr[node], e1 = ptr[node + 1];
  float4 a = make_float4(0.f, 0.f, 0.f, 0.f);
  int e = e0;
  if ((e & 1) && e < e1) {
    int2 p = ep[e];
    float w0 = __int_as_float(p.y);
    float4 h = hin[(size_t)p.x * F4 + f4];
    a.x += w0 * h.x; a.y += w0 * h.y; a.z += w0 * h.z; a.w += w0 * h.w;
    ++e;
  }
  for (; e + 1 < e1; e += 2) {
    int4 p = *(const int4*)(ep + e);  // 2 edges, 16B aligned
    float w0 = __int_as_float(p.y), w1 = __int_as_float(p.w);
    float4 h0 = hin[(size_t)p.x * F4 + f4];
    float4 h1 = hin[(size_t)p.z * F4 + f4];
    a.x += w0 * h0.x; a.y += w0 * h0.y; a.z += w0 * h0.z; a.w += w0 * h0.w;
    a.x += w1 * h1.x; a.y += w1 * h1.y; a.z += w1 * h1.z; a.w += w1 * h1.w;
  }
  if (e < e1) {
    int2 p = ep[e];
    float w0 = __int_as_float(p.y);
    float4 h = hin[(size_t)p.x * F4 + f4];
    a.x += w0 * h.x; a.y += w0 * h.y; a.z += w0 * h.z; a.w += w0 * h.w;
  }
  return a;
}

// ---------- fused prop + matmul, F=64 (16 lanes/node, 16 nodes/block) ----------
// t = A*hin; if !LAST write t->hout; acc (+)= t@Wk [+ hin_own@W0 if FIRST];
// if LAST: +bias, leaky -> hout (or head reduce -> outv if HEAD).
template <bool FIRST, bool LAST, bool HEAD>
__launch_bounds__(256)
__global__ void ptag64_k(const int* __restrict__ ptr, const int2* __restrict__ ep,
                         const float4* __restrict__ hin, float4* __restrict__ hout,
                         const float4* __restrict__ Wk4, const float4* __restrict__ W04,
                         float4* __restrict__ acc4, const float4* __restrict__ bias4,
                         const float* __restrict__ Wout, const float* __restrict__ bout,
                         float* __restrict__ outv, int n) {
  __shared__ float4 Wl[1024];               // 64x64 W_k
  __shared__ float4 W0l[FIRST ? 1024 : 1];  // 64x64 W_0 (FIRST only)
  __shared__ float4 tl4[16 * 17];           // t tile, stride 17 float4 (bank-clean)
  const float* tl = (const float*)tl4;
  int tid = threadIdx.x;
  for (int i = tid; i < 1024; i += 256) Wl[i] = Wk4[i];
  if (FIRST)
    for (int i = tid; i < 1024; i += 256) W0l[i] = W04[i];
  int gid = blockIdx.x * 256 + tid;
  int node = gid >> 4, j4 = gid & 15, ln = tid >> 4;

  float4 t = make_float4(0.f, 0.f, 0.f, 0.f);
  if (node < n) {
    t = gather<16>(ptr, ep, hin, node, j4);
    if (!LAST) hout[(size_t)node * 16 + j4] = t;
  }
  tl4[ln * 17 + j4] = t;
  __syncthreads();

  float4 a = make_float4(0.f, 0.f, 0.f, 0.f);
  if (!FIRST && node < n) a = acc4[(size_t)node * 16 + j4];
#pragma unroll 8
  for (int i = 0; i < 64; ++i) {
    float tv = tl[ln * 68 + i];
    float4 wv = Wl[i * 16 + j4];
    a.x = fmaf(tv, wv.x, a.x); a.y = fmaf(tv, wv.y, a.y);
    a.z = fmaf(tv, wv.z, a.z); a.w = fmaf(tv, wv.w, a.w);
  }
  if (FIRST) {  // own-term h0 @ W0, reusing the tile
    __syncthreads();
    float4 own = (node < n) ? hin[(size_t)node * 16 + j4] : make_float4(0.f, 0.f, 0.f, 0.f);
    tl4[ln * 17 + j4] = own;
    __syncthreads();
#pragma unroll 8
    for (int i = 0; i < 64; ++i) {
      float tv = tl[ln * 68 + i];
      float4 wv = W0l[i * 16 + j4];
      a.x = fmaf(tv, wv.x, a.x); a.y = fmaf(tv, wv.y, a.y);
      a.z = fmaf(tv, wv.z, a.z); a.w = fmaf(tv, wv.w, a.w);
    }
  }
  if (node >= n) return;  // no barriers below

  if (LAST) {
    float4 b = bias4[j4];
    a.x += b.x; a.y += b.y; a.z += b.z; a.w += b.w;
    a.x = (a.x >= 0.f) ? a.x : 0.01f * a.x;
    a.y = (a.y >= 0.f) ? a.y : 0.01f * a.y;
    a.z = (a.z >= 0.f) ? a.z : 0.01f * a.z;
    a.w = (a.w >= 0.f) ? a.w : 0.01f * a.w;
    if (HEAD) {
      float v = a.x * Wout[4 * j4] + a.y * Wout[4 * j4 + 1] +
                a.z * Wout[4 * j4 + 2] + a.w * Wout[4 * j4 + 3];
      v += __shfl_down(v, 8, 16);
      v += __shfl_down(v, 4, 16);
      v += __shfl_down(v, 2, 16);
      v += __shfl_down(v, 1, 16);
      if (j4 == 0) outv[node] = v + bout[0];
    } else {
      hout[(size_t)node * 16 + j4] = a;  // activated layer output
    }
  } else {
    acc4[(size_t)node * 16 + j4] = a;
  }
}

// ---------- fused prop + matmul, layer 1: F_in=16 (4 lanes/node, 64 nodes/block) ----------
template <bool FIRST, bool LAST>
__launch_bounds__(256)
__global__ void ptag16_k(const int* __restrict__ ptr, const int2* __restrict__ ep,
                         const float4* __restrict__ hin, float4* __restrict__ hout,
                         const float4* __restrict__ Wk4, const float4* __restrict__ W04,
                         float4* __restrict__ acc4, const float4* __restrict__ bias4,
                         float4* __restrict__ outbuf, int n) {
  __shared__ float4 Wl[256];               // 16x64 W_k
  __shared__ float4 W0l[FIRST ? 256 : 1];  // 16x64 W_0
  __shared__ float4 tl4[64 * 5];           // t tile, stride 5 float4
  const float* tl = (const float*)tl4;
  int tid = threadIdx.x;
  Wl[tid] = Wk4[tid];
  if (FIRST) W0l[tid] = W04[tid];
  int gid = blockIdx.x * 256 + tid;
  int node = gid >> 2, q = tid & 3, ln = tid >> 2;

  float4 t = make_float4(0.f, 0.f, 0.f, 0.f);
  if (node < n) {
    t = gather<4>(ptr, ep, hin, node, q);
    if (!LAST) hout[(size_t)node * 4 + q] = t;
  }
  tl4[ln * 5 + q] = t;
  __syncthreads();

  float4 a[4];
#pragma unroll
  for (int c = 0; c < 4; ++c) a[c] = make_float4(0.f, 0.f, 0.f, 0.f);
  if (!FIRST && node < n) {
#pragma unroll
    for (int c = 0; c < 4; ++c) a[c] = acc4[(size_t)node * 16 + 4 * q + c];
  }
#pragma unroll 4
  for (int i = 0; i < 16; ++i) {
    float tv = tl[ln * 20 + i];
#pragma unroll
    for (int c = 0; c < 4; ++c) {
      float4 wv = Wl[i * 16 + 4 * q + c];
      a[c].x = fmaf(tv, wv.x, a[c].x); a[c].y = fmaf(tv, wv.y, a[c].y);
      a[c].z = fmaf(tv, wv.z, a[c].z); a[c].w = fmaf(tv, wv.w, a[c].w);
    }
  }
  if (FIRST) {  // own-term x @ W0
    __syncthreads();
    float4 own = (node < n) ? hin[(size_t)node * 4 + q] : make_float4(0.f, 0.f, 0.f, 0.f);
    tl4[ln * 5 + q] = own;
    __syncthreads();
#pragma unroll 4
    for (int i = 0; i < 16; ++i) {
      float tv = tl[ln * 20 + i];
#pragma unroll
      for (int c = 0; c < 4; ++c) {
        float4 wv = W0l[i * 16 + 4 * q + c];
        a[c].x = fmaf(tv, wv.x, a[c].x); a[c].y = fmaf(tv, wv.y, a[c].y);
        a[c].z = fmaf(tv, wv.z, a[c].z); a[c].w = fmaf(tv, wv.w, a[c].w);
      }
    }
  }
  if (node >= n) return;

  if (LAST) {
#pragma unroll
    for (int c = 0; c < 4; ++c) {
      float4 b = bias4[4 * q + c];
      a[c].x += b.x; a[c].y += b.y; a[c].z += b.z; a[c].w += b.w;
      a[c].x = (a[c].x >= 0.f) ? a[c].x : 0.01f * a[c].x;
      a[c].y = (a[c].y >= 0.f) ? a[c].y : 0.01f * a[c].y;
      a[c].z = (a[c].z >= 0.f) ? a[c].z : 0.01f * a[c].z;
      a[c].w = (a[c].w >= 0.f) ? a[c].w : 0.01f * a[c].w;
      outbuf[(size_t)node * 16 + 4 * q + c] = a[c];  // activated, F=64 layout
    }
  } else {
#pragma unroll
    for (int c = 0; c < 4; ++c) acc4[(size_t)node * 16 + 4 * q + c] = a[c];
  }
}

extern "C" void kernel_launch(void* const* d_in, const int* in_sizes, int n_in,
                              void* d_out, int out_size, void* d_ws, size_t ws_size,
                              hipStream_t stream) {
  const float* x    = (const float*)d_in[0];
  const int*   ei   = (const int*)d_in[1];
  const float* ew   = (const float*)d_in[2];
  const float* W1   = (const float*)d_in[4];
  const float* b1   = (const float*)d_in[5];
  const float* W2   = (const float*)d_in[6];
  const float* b2   = (const float*)d_in[7];
  const float* Wout = (const float*)d_in[8];
  const float* bout = (const float*)d_in[9];
  float* out = (float*)d_out;

  const int N = in_sizes[0] / 16;
  const int E = in_sizes[2];
  const int* src = ei;
  const int* dst = ei + E;

  char* ws = (char*)d_ws;
  size_t off = 0;
  auto alloc = [&](size_t bytes) {
    char* p = ws + off;
    off = (off + bytes + 255) & ~(size_t)255;
    return p;
  };
  u64*   pack = (u64*)alloc((size_t)N * 8);
  float* dinv = (float*)alloc((size_t)N * 4);
  int*   ptr  = (int*)alloc(((size_t)N + 1) * 4);
  int*   bsum = (int*)alloc(4096);
  int*   rank = (int*)alloc((size_t)E * 4);
  int2*  ep   = (int2*)alloc((size_t)E * 8);
  float* B0   = (float*)alloc((size_t)N * 64 * 4);
  float* B1   = (float*)alloc((size_t)N * 64 * 4);
  float* B2   = (float*)alloc((size_t)N * 64 * 4);

  hipMemsetAsync(pack, 0, (size_t)N * 8, stream);

  int gE = (E + 255) / 256;
  int gN = (N + 255) / 256;
  degcount_k<<<gE, 256, 0, stream>>>(dst, ew, pack, rank, E);
  scan_blocks<<<gN, 256, 0, stream>>>(pack, dinv, ptr, bsum, N);
  scan_sums<<<1, 512, 0, stream>>>(bsum, gN);
  scan_add<<<gN, 256, 0, stream>>>(ptr, bsum, N, E);
  fill_k<<<gE, 256, 0, stream>>>(src, dst, ew, dinv, ptr, rank, ep, E);

  int g4  = (N * 4 + 255) / 256;   // layer-1 fused (4 lanes/node)
  int g16 = (N * 16 + 255) / 256;  // F=64 fused (16 lanes/node)

  const float4* x4 = (const float4*)x;
  float4* B04 = (float4*)B0; float4* B14 = (float4*)B1; float4* B24 = (float4*)B2;
  auto W1k = [&](int k) { return (const float4*)(W1 + (size_t)k * 1024); };
  auto W2k = [&](int l, int k) { return (const float4*)(W2 + ((size_t)l * 5 + k) * 4096); };

  // ---- Layer 1 (16 -> 64): acc in B2, t ping-pong B0/B1, output -> B1 ----
  ptag16_k<true,  false><<<g4, 256, 0, stream>>>(ptr, ep, x4,  B04, W1k(1), W1k(0), B24, nullptr, nullptr, N);
  ptag16_k<false, false><<<g4, 256, 0, stream>>>(ptr, ep, B04, B14, W1k(2), nullptr, B24, nullptr, nullptr, N);
  ptag16_k<false, false><<<g4, 256, 0, stream>>>(ptr, ep, B14, B04, W1k(3), nullptr, B24, nullptr, nullptr, N);
  ptag16_k<false, true ><<<g4, 256, 0, stream>>>(ptr, ep, B04, nullptr, W1k(4), nullptr, B24,
                                                 (const float4*)b1, B14, N);

  // ---- Layer 2 (64 -> 64): input B1, acc B2, output -> B1 ----
  ptag64_k<true,  false, false><<<g16, 256, 0, stream>>>(ptr, ep, B14, B04, W2k(0,1), W2k(0,0), B24,
                                                         nullptr, nullptr, nullptr, nullptr, N);
  ptag64_k<false, false, false><<<g16, 256, 0, stream>>>(ptr, ep, B04, B14, W2k(0,2), nullptr, B24,
                                                         nullptr, nullptr, nullptr, nullptr, N);
  ptag64_k<false, false, false><<<g16, 256, 0, stream>>>(ptr, ep, B14, B04, W2k(0,3), nullptr, B24,
                                                         nullptr, nullptr, nullptr, nullptr, N);
  ptag64_k<false, true,  false><<<g16, 256, 0, stream>>>(ptr, ep, B04, B14, W2k(0,4), nullptr, B24,
                                                         (const float4*)b2, nullptr, nullptr, nullptr, N);

  // ---- Layer 3 (64 -> 64) + head: input B1, acc B2, head -> out ----
  ptag64_k<true,  false, false><<<g16, 256, 0, stream>>>(ptr, ep, B14, B04, W2k(1,1), W2k(1,0), B24,
                                                         nullptr, nullptr, nullptr, nullptr, N);
  ptag64_k<false, false, false><<<g16, 256, 0, stream>>>(ptr, ep, B04, B14, W2k(1,2), nullptr, B24,
                                                         nullptr, nullptr, nullptr, nullptr, N);
  ptag64_k<false, false, false><<<g16, 256, 0, stream>>>(ptr, ep, B14, B04, W2k(1,3), nullptr, B24,
                                                         nullptr, nullptr, nullptr, nullptr, N);
  ptag64_k<false, true,  true ><<<g16, 256, 0, stream>>>(ptr, ep, B04, nullptr, W2k(1,4), nullptr, B24,
                                                         (const float4*)(b2 + 64), Wout, bout, out, N);
}